// Round 11
// baseline (1051.888 us; speedup 1.0000x reference)
//
#include <hip/hip_runtime.h>

// APPNP link-prediction: N=100000, F=256, H=128, E=1.6M, K=10 x 2 layers.
// CSR-by-dst (self-loops folded, 0.9*norm pre-folded), gather-only SpMV hops.
// z stored fp8 e4m3 during hops (128B rows = 1 line per gather); final hop of
// each layer reads fp8 and emits bf16 (relu'd for L2's GEMM input).
// GEMMs: v_mfma_f32_16x16x32_bf16. k_place: 4 edges/thread for scatter MLP.

constexpr int Hd = 128;
constexpr int Fin = 256;
constexpr float A_ = 0.1f;
constexpr float OMA = 0.9f;

typedef float vf2 __attribute__((ext_vector_type(2)));
typedef __bf16 bf16x8 __attribute__((ext_vector_type(8)));
typedef float f32x4 __attribute__((ext_vector_type(4)));

__device__ __forceinline__ int idx_at(const void* p, size_t i, int is64) {
    if (is64) return (int)((const long long*)p)[i];
    return ((const int*)p)[i];
}

__device__ __forceinline__ unsigned short bf16_of(float x) {
    unsigned u = __float_as_uint(x);
    return (unsigned short)((u + 0x7fffu + ((u >> 16) & 1u)) >> 16);
}

__device__ __forceinline__ unsigned pack_bf16x2(float x, float y) {
    unsigned ux = __float_as_uint(x);
    unsigned uy = __float_as_uint(y);
    ux = (ux + 0x7fffu + ((ux >> 16) & 1u)) >> 16;          // RNE
    uy = (uy + 0x7fffu + ((uy >> 16) & 1u)) & 0xffff0000u;  // RNE, keep high
    return ux | uy;
}

__device__ __forceinline__ float2 unpack_bf16x2(unsigned v) {
    float2 r;
    r.x = __uint_as_float(v << 16);
    r.y = __uint_as_float(v & 0xffff0000u);
    return r;
}

__device__ __forceinline__ unsigned short pack_fp8x2(float x, float y) {
    int v = __builtin_amdgcn_cvt_pk_fp8_f32(x, y, 0, false);   // low word
    return (unsigned short)(unsigned)v;
}

__device__ __forceinline__ float2 unpack_fp8x2(unsigned short v) {
    vf2 r = __builtin_amdgcn_cvt_pk_f32_fp8((int)(unsigned)v, false);
    float2 o;
    o.x = r[0];
    o.y = r[1];
    return o;
}

// ---------------- dtype probe ----------------
__global__ void k_detect(const int* __restrict__ p, int npairs, int* __restrict__ flag) {
    __shared__ int any32;
    if (threadIdx.x == 0) any32 = 0;
    __syncthreads();
    for (int i = threadIdx.x; i < npairs; i += blockDim.x)
        if (p[2 * i + 1] != 0) any32 = 1;
    __syncthreads();
    if (threadIdx.x == 0) *flag = any32 ? 0 : 1;   // 1 => int64
}

// ---------------- preprocessing ----------------

__global__ void k_zero_i32(int* __restrict__ p, int n) {
    int i = blockIdx.x * blockDim.x + threadIdx.x;
    if (i < n) p[i] = 0;
}

__global__ void k_count(const void* __restrict__ ei, int E, int* __restrict__ cnt,
                        const int* __restrict__ flag) {
    int is64 = *flag;
    int e = blockIdx.x * blockDim.x + threadIdx.x;
    if (e < E) {
        int d = idx_at(ei, (size_t)E + e, is64);
        atomicAdd(&cnt[d], 1);
    }
}

__global__ void k_dinv(const int* __restrict__ cnt, float* __restrict__ dinv, int N) {
    int i = blockIdx.x * blockDim.x + threadIdx.x;
    if (i < N) dinv[i] = rsqrtf((float)(cnt[i] + 1));
}

__global__ void k_scan1(const int* __restrict__ cnt, int* __restrict__ rp,
                        int* __restrict__ bsum, int N) {
    __shared__ int s[256];
    int t = threadIdx.x;
    int i = blockIdx.x * 256 + t;
    int v = (i < N) ? (cnt[i] + 1) : 0;   // +1 self-loop slot
    s[t] = v;
    __syncthreads();
    for (int off = 1; off < 256; off <<= 1) {
        int add = (t >= off) ? s[t - off] : 0;
        __syncthreads();
        s[t] += add;
        __syncthreads();
    }
    if (i < N) rp[i] = s[t] - v;
    if (t == 255) bsum[blockIdx.x] = s[255];
}

__global__ void k_scan2(int* __restrict__ bsum, int nb) {
    __shared__ int s[512];
    int t = threadIdx.x;
    int v = (t < nb) ? bsum[t] : 0;
    s[t] = v;
    __syncthreads();
    for (int off = 1; off < 512; off <<= 1) {
        int add = (t >= off) ? s[t - off] : 0;
        __syncthreads();
        s[t] += add;
        __syncthreads();
    }
    if (t < nb) bsum[t] = s[t] - v;
}

__global__ void k_scan3(int* __restrict__ rp, const int* __restrict__ bsum,
                        int* __restrict__ cursor, const float* __restrict__ dinv,
                        int2* __restrict__ cw, int N, int Etot) {
    int i = blockIdx.x * blockDim.x + threadIdx.x;
    if (i < N) {
        int r = rp[i] + bsum[i >> 8];
        rp[i] = r;
        cursor[i] = 1;
        float d = dinv[i];
        int2 p;
        p.x = i;
        p.y = __float_as_int(OMA * d * d);
        cw[r] = p;   // self-loop first in each row
    }
    if (i == 0) rp[N] = Etot;
}

// 4 edges per thread: 4 independent atomic+store chains in flight.
__global__ __launch_bounds__(256) void k_place(const void* __restrict__ ei, int E,
                                               const int* __restrict__ rp,
                                               int* __restrict__ cursor,
                                               const float* __restrict__ dinv,
                                               int2* __restrict__ cw,
                                               const int* __restrict__ flag) {
    const int is64 = *flag;
    const int e0 = (blockIdx.x * blockDim.x + threadIdx.x) * 4;
    if (e0 >= E) return;
    const int n = min(4, E - e0);
    int s[4], d[4];
#pragma unroll
    for (int k = 0; k < 4; ++k) {
        int e = e0 + min(k, n - 1);
        s[k] = idx_at(ei, (size_t)e, is64);
        d[k] = idx_at(ei, (size_t)E + e, is64);
    }
    int pos[4];
#pragma unroll
    for (int k = 0; k < 4; ++k)
        if (k < n) pos[k] = rp[d[k]] + atomicAdd(&cursor[d[k]], 1);
    float ws[4], wd[4];
#pragma unroll
    for (int k = 0; k < 4; ++k) {
        ws[k] = dinv[s[k]];
        wd[k] = dinv[d[k]];
    }
#pragma unroll
    for (int k = 0; k < 4; ++k)
        if (k < n) {
            int2 p;
            p.x = s[k];
            p.y = __float_as_int(OMA * ws[k] * wd[k]);
            cw[pos[k]] = p;
        }
}

// ---------------- W transpose+cvt: Wt[c][k] = bf16(W[k][c]), W is [K][128] ----------------
__global__ void k_wt(const float* __restrict__ W, unsigned short* __restrict__ Wt, int K) {
    int i = blockIdx.x * blockDim.x + threadIdx.x;
    if (i < K * 128) {
        int k = i >> 7, c = i & 127;
        Wt[c * K + k] = bf16_of(W[i]);
    }
}

// ---------------- MFMA GEMM: z0 fp8 + alpha*h bf16 from A[N][KTOT] @ W[KTOT][128] ----------------

template <int KTOT, bool AF32>
__global__ __launch_bounds__(256) void k_gemm_mfma(const void* __restrict__ Ap,
                                                   const unsigned short* __restrict__ Wt,
                                                   unsigned short* __restrict__ z0,
                                                   unsigned* __restrict__ ah, int N) {
    __shared__ __align__(16) char smem[64 * 132 * 4];
    unsigned short (*As)[40] = (unsigned short(*)[40])smem;            // 64 x 32 (+8 pad)
    unsigned short (*Bs)[40] = (unsigned short(*)[40])(smem + 5120);   // 128 x 32 (+8 pad), [col][k]
    float (*Cs)[132] = (float(*)[132])smem;

    const int t    = threadIdx.x;
    const int lane = t & 63;
    const int w    = t >> 6;
    const int wr   = w >> 1;
    const int wc   = w & 1;
    const int r0   = blockIdx.x * 64;

    f32x4 acc[2][4];
#pragma unroll
    for (int i = 0; i < 2; ++i)
#pragma unroll
        for (int j = 0; j < 4; ++j)
#pragma unroll
            for (int q = 0; q < 4; ++q) acc[i][j][q] = 0.f;

    const int arow = t >> 2;
    const int akc  = (t & 3) * 8;
    const int bcol = t >> 1;
    const int bkc  = (t & 1) * 16;

    for (int k0 = 0; k0 < KTOT; k0 += 32) {
        {
            int gr = r0 + arow;
            if (AF32) {
                uint4 s = make_uint4(0, 0, 0, 0);
                if (gr < N) {
                    const float* a = (const float*)Ap + (size_t)gr * KTOT + k0 + akc;
                    float4 v0 = *(const float4*)a;
                    float4 v1 = *(const float4*)(a + 4);
                    s.x = pack_bf16x2(v0.x, v0.y);
                    s.y = pack_bf16x2(v0.z, v0.w);
                    s.z = pack_bf16x2(v1.x, v1.y);
                    s.w = pack_bf16x2(v1.z, v1.w);
                }
                *(uint4*)&As[arow][akc] = s;
            } else {
                uint4 s = make_uint4(0, 0, 0, 0);
                if (gr < N) s = *(const uint4*)((const unsigned short*)Ap + (size_t)gr * KTOT + k0 + akc);
                *(uint4*)&As[arow][akc] = s;
            }
        }
        {
            const unsigned short* wsrc = Wt + (size_t)bcol * KTOT + k0 + bkc;
            *(uint4*)&Bs[bcol][bkc]     = *(const uint4*)wsrc;
            *(uint4*)&Bs[bcol][bkc + 8] = *(const uint4*)(wsrc + 8);
        }
        __syncthreads();
        {
            const int kblk = (lane >> 4) * 8;
            const int l15  = lane & 15;
            bf16x8 af[2], bfr[4];
#pragma unroll
            for (int i = 0; i < 2; ++i)
                af[i] = *(const bf16x8*)&As[wr * 32 + i * 16 + l15][kblk];
#pragma unroll
            for (int j = 0; j < 4; ++j)
                bfr[j] = *(const bf16x8*)&Bs[wc * 64 + j * 16 + l15][kblk];
#pragma unroll
            for (int i = 0; i < 2; ++i)
#pragma unroll
                for (int j = 0; j < 4; ++j)
                    acc[i][j] = __builtin_amdgcn_mfma_f32_16x16x32_bf16(af[i], bfr[j], acc[i][j], 0, 0, 0);
        }
        __syncthreads();
    }

    {
        const int l15 = lane & 15;
        const int rq  = (lane >> 4) * 4;
#pragma unroll
        for (int i = 0; i < 2; ++i)
#pragma unroll
            for (int j = 0; j < 4; ++j)
#pragma unroll
                for (int q = 0; q < 4; ++q)
                    Cs[wr * 32 + i * 16 + rq + q][wc * 64 + j * 16 + l15] = acc[i][j][q];
    }
    __syncthreads();
    {
        const int row = t >> 2;
        const int cb  = (t & 3) * 32;
        const int gr  = r0 + row;
        if (gr < N) {
            float c[32];
#pragma unroll
            for (int m = 0; m < 8; ++m) {
                float4 v = *(const float4*)&Cs[row][cb + m * 4];
                c[m * 4 + 0] = v.x; c[m * 4 + 1] = v.y; c[m * 4 + 2] = v.z; c[m * 4 + 3] = v.w;
            }
            unsigned pk[8];
#pragma unroll
            for (int m = 0; m < 8; ++m) {
                unsigned lo = (unsigned)pack_fp8x2(c[4 * m + 0], c[4 * m + 1]);
                unsigned hi = (unsigned)pack_fp8x2(c[4 * m + 2], c[4 * m + 3]);
                pk[m] = lo | (hi << 16);
            }
            uint4* zd = (uint4*)&z0[((size_t)gr << 6) + (cb >> 1)];
            zd[0] = make_uint4(pk[0], pk[1], pk[2], pk[3]);
            zd[1] = make_uint4(pk[4], pk[5], pk[6], pk[7]);
            unsigned am[16];
#pragma unroll
            for (int m = 0; m < 16; ++m)
                am[m] = pack_bf16x2(A_ * c[2 * m], A_ * c[2 * m + 1]);
            uint4* ad = (uint4*)&ah[((size_t)gr << 6) + (cb >> 1)];
            ad[0] = make_uint4(am[0],  am[1],  am[2],  am[3]);
            ad[1] = make_uint4(am[4],  am[5],  am[6],  am[7]);
            ad[2] = make_uint4(am[8],  am[9],  am[10], am[11]);
            ad[3] = make_uint4(am[12], am[13], am[14], am[15]);
        }
    }
}

// ---------------- propagation hop ----------------
// IN8: 1 = fp8 input rows (128B), 0 = bf16 (256B). OUTM: 0 fp8, 1 bf16, 3 relu+bf16.

template <int B, int IN8>
__device__ __forceinline__ void hop_batch(const void* __restrict__ zb,
                                          const int2* __restrict__ cw,
                                          int e, int lane,
                                          float& ax, float& ay,
                                          float& bx, float& by) {
    int2 p[B];
#pragma unroll
    for (int k = 0; k < B; ++k) p[k] = cw[e + k];
    unsigned zv[B];
#pragma unroll
    for (int k = 0; k < B; ++k) {
        if (IN8) zv[k] = ((const unsigned short*)zb)[((unsigned)p[k].x << 6) + lane];
        else     zv[k] = ((const unsigned*)zb)[((unsigned)p[k].x << 6) + lane];
    }
#pragma unroll
    for (int k = 0; k < B; ++k) {
        float wv = __int_as_float(p[k].y);
        float2 z = IN8 ? unpack_fp8x2((unsigned short)zv[k]) : unpack_bf16x2(zv[k]);
        if (k & 1) { bx = fmaf(wv, z.x, bx); by = fmaf(wv, z.y, by); }
        else       { ax = fmaf(wv, z.x, ax); ay = fmaf(wv, z.y, ay); }
    }
}

template <int IN8, int OUTM>
__global__ __launch_bounds__(256) void k_hop(const void* __restrict__ zin,
                                             const unsigned* __restrict__ ah,
                                             void* __restrict__ zout,
                                             const int* __restrict__ rp,
                                             const int2* __restrict__ cw, int N) {
    int wid  = (blockIdx.x * blockDim.x + threadIdx.x) >> 6;
    int lane = threadIdx.x & 63;
    if (wid >= N) return;

    int e   = __builtin_amdgcn_readfirstlane(rp[wid]);
    int end = __builtin_amdgcn_readfirstlane(rp[wid + 1]);

    float2 hh = unpack_bf16x2(ah[((size_t)wid << 6) + lane]);

    float ax = 0.f, ay = 0.f, bx = 0.f, by = 0.f;

    for (; e + 16 <= end; e += 16)
        hop_batch<16, IN8>(zin, cw, e, lane, ax, ay, bx, by);
    if (e + 8 <= end) { hop_batch<8, IN8>(zin, cw, e, lane, ax, ay, bx, by); e += 8; }
    if (e + 4 <= end) { hop_batch<4, IN8>(zin, cw, e, lane, ax, ay, bx, by); e += 4; }
    for (; e < end; ++e) {
        int2 p = cw[e];
        unsigned zv;
        if (IN8) zv = ((const unsigned short*)zin)[((unsigned)p.x << 6) + lane];
        else     zv = ((const unsigned*)zin)[((unsigned)p.x << 6) + lane];
        float2 z = IN8 ? unpack_fp8x2((unsigned short)zv) : unpack_bf16x2(zv);
        float wv = __int_as_float(p.y);
        ax = fmaf(wv, z.x, ax); ay = fmaf(wv, z.y, ay);
    }

    float ox = (ax + bx) + hh.x;
    float oy = (ay + by) + hh.y;
    if (OUTM == 0) {
        ((unsigned short*)zout)[((size_t)wid << 6) + lane] = pack_fp8x2(ox, oy);
    } else if (OUTM == 1) {
        ((unsigned*)zout)[((size_t)wid << 6) + lane] = pack_bf16x2(ox, oy);
    } else {
        ((unsigned*)zout)[((size_t)wid << 6) + lane] =
            pack_bf16x2(fmaxf(ox, 0.f), fmaxf(oy, 0.f));
    }
}

// ---------------- decode: out[j] = dot(z[e0[j]], z[e1[j]]), z bf16 ----------------

__global__ __launch_bounds__(256) void k_decode(const unsigned* __restrict__ z,
                                                const void* __restrict__ pos,
                                                const void* __restrict__ neg,
                                                float* __restrict__ out, int P, int Q,
                                                const int* __restrict__ flag) {
    int is64 = *flag;
    int t   = blockIdx.x * blockDim.x + threadIdx.x;
    int j   = t >> 4;
    int sub = t & 15;
    if (j >= P + Q) return;
    int a, b;
    if (j < P) { a = idx_at(pos, (size_t)j, is64); b = idx_at(pos, (size_t)P + j, is64); }
    else       { int jj = j - P; a = idx_at(neg, (size_t)jj, is64); b = idx_at(neg, (size_t)Q + jj, is64); }
    const uint4* za = (const uint4*)&z[(size_t)a << 6];
    const uint4* zb = (const uint4*)&z[(size_t)b << 6];
    uint4 va = za[sub];
    uint4 vb = zb[sub];
    float s = 0.f;
    {
        float2 xa, xb;
        xa = unpack_bf16x2(va.x); xb = unpack_bf16x2(vb.x);
        s += xa.x * xb.x + xa.y * xb.y;
        xa = unpack_bf16x2(va.y); xb = unpack_bf16x2(vb.y);
        s += xa.x * xb.x + xa.y * xb.y;
        xa = unpack_bf16x2(va.z); xb = unpack_bf16x2(vb.z);
        s += xa.x * xb.x + xa.y * xb.y;
        xa = unpack_bf16x2(va.w); xb = unpack_bf16x2(vb.w);
        s += xa.x * xb.x + xa.y * xb.y;
    }
#pragma unroll
    for (int off = 8; off >= 1; off >>= 1) s += __shfl_xor(s, off, 16);
    if (sub == 0) out[j] = s;
}

// ---------------- launch ----------------

extern "C" void kernel_launch(void* const* d_in, const int* in_sizes, int n_in,
                              void* d_out, int out_size, void* d_ws, size_t ws_size,
                              hipStream_t stream) {
    const float* x   = (const float*)d_in[0];
    const void*  ei  = d_in[1];
    const void*  pos = d_in[2];
    const void*  neg = d_in[3];
    const float* W1  = (const float*)d_in[4];
    const float* W2  = (const float*)d_in[5];
    float*       out = (float*)d_out;

    const int N = in_sizes[0] / Fin;
    const int E = in_sizes[1] / 2;
    const int P = in_sizes[2] / 2;
    const int Q = in_sizes[3] / 2;
    const int Etot = E + N;

    char*  ws  = (char*)d_ws;
    size_t off = 0;
    auto carve = [&](size_t bytes) -> void* {
        void* p = ws + off;
        off = (off + bytes + 511) & ~(size_t)511;
        return p;
    };
    unsigned short* f0   = (unsigned short*)carve((size_t)N * 64 * 2);
    unsigned short* f1   = (unsigned short*)carve((size_t)N * 64 * 2);
    unsigned*       zB2  = (unsigned*)carve((size_t)N * 64 * 4);   // bf16 final (decode)
    unsigned*       zRB  = (unsigned*)carve((size_t)N * 64 * 4);   // relu bf16 (L2 GEMM A)
    unsigned*       ah   = (unsigned*)carve((size_t)N * 64 * 4);
    unsigned short* Wt1  = (unsigned short*)carve((size_t)128 * 256 * 2);
    unsigned short* Wt2  = (unsigned short*)carve((size_t)128 * 128 * 2);
    float*          dinv = (float*)carve((size_t)N * 4);
    int*     cnt    = (int*)carve((size_t)N * 4);
    int*     rp     = (int*)carve((size_t)(N + 1) * 4);
    int*     cursor = (int*)carve((size_t)N * 4);
    int2*    cw     = (int2*)carve((size_t)Etot * 8);
    int      nb     = (N + 255) / 256;
    int*     bsum   = (int*)carve((size_t)nb * 4);
    int*     flag   = (int*)carve(4);
    (void)ws_size;

    const int gN = (N + 255) / 256;
    const int gE = (E + 255) / 256;

    k_detect<<<1, 256, 0, stream>>>((const int*)ei, 4096, flag);
    k_zero_i32<<<gN, 256, 0, stream>>>(cnt, N);
    k_count<<<gE, 256, 0, stream>>>(ei, E, cnt, flag);
    k_dinv<<<gN, 256, 0, stream>>>(cnt, dinv, N);
    k_scan1<<<nb, 256, 0, stream>>>(cnt, rp, bsum, N);
    k_scan2<<<1, 512, 0, stream>>>(bsum, nb);
    k_scan3<<<gN, 256, 0, stream>>>(rp, bsum, cursor, dinv, cw, N, Etot);
    k_place<<<(E + 1023) / 1024, 256, 0, stream>>>(ei, E, rp, cursor, dinv, cw, flag);
    k_wt<<<(256 * 128 + 255) / 256, 256, 0, stream>>>(W1, Wt1, Fin);
    k_wt<<<(128 * 128 + 255) / 256, 256, 0, stream>>>(W2, Wt2, Hd);

    const int gGemm = (N + 63) / 64;
    const int gHop  = (N * 64 + 255) / 256;

    unsigned short* fb[2] = {f0, f1};

    // ---- layer 1: GEMM -> 9 fp8 hops -> final hop reads fp8, writes relu-bf16 ----
    k_gemm_mfma<Fin, true><<<gGemm, 256, 0, stream>>>(x, Wt1, f0, ah, N);
    for (int k = 0; k < 9; ++k)
        k_hop<1, 0><<<gHop, 256, 0, stream>>>(fb[k & 1], ah, fb[(k + 1) & 1], rp, cw, N);
    k_hop<1, 3><<<gHop, 256, 0, stream>>>(f1, ah, zRB, rp, cw, N);

    // ---- layer 2: GEMM -> 9 fp8 hops -> final hop reads fp8, writes bf16 ----
    k_gemm_mfma<Hd, false><<<gGemm, 256, 0, stream>>>(zRB, Wt2, f0, ah, N);
    for (int k = 0; k < 9; ++k)
        k_hop<1, 0><<<gHop, 256, 0, stream>>>(fb[k & 1], ah, fb[(k + 1) & 1], rp, cw, N);
    k_hop<1, 1><<<gHop, 256, 0, stream>>>(f1, ah, zB2, rp, cw, N);

    // ---- decode (bf16 z) ----
    const int gDec = ((P + Q) * 16 + 255) / 256;
    k_decode<<<gDec, 256, 0, stream>>>(zB2, pos, neg, out, P, Q, flag);
}

// Round 12
// 1042.421 us; speedup vs baseline: 1.0091x; 1.0091x over previous
//
#include <hip/hip_runtime.h>

// APPNP link-prediction: N=100000, F=256, H=128, E=1.6M, K=10 x 2 layers.
// CSR-by-dst with WEIGHTLESS edges (4B col only): store y = dinv*z; then
// sum_e norm*z = dinv[d] * sum y[src]. z in fp8 e4m3 during hops (128B rows);
// final hops emit bf16 z (relu'd for L2 GEMM). GEMMs: v_mfma_f32_16x16x32_bf16.

constexpr int Hd = 128;
constexpr int Fin = 256;
constexpr float A_ = 0.1f;
constexpr float OMA = 0.9f;

typedef float vf2 __attribute__((ext_vector_type(2)));
typedef __bf16 bf16x8 __attribute__((ext_vector_type(8)));
typedef float f32x4 __attribute__((ext_vector_type(4)));

__device__ __forceinline__ int idx_at(const void* p, size_t i, int is64) {
    if (is64) return (int)((const long long*)p)[i];
    return ((const int*)p)[i];
}

__device__ __forceinline__ unsigned short bf16_of(float x) {
    unsigned u = __float_as_uint(x);
    return (unsigned short)((u + 0x7fffu + ((u >> 16) & 1u)) >> 16);
}

__device__ __forceinline__ unsigned pack_bf16x2(float x, float y) {
    unsigned ux = __float_as_uint(x);
    unsigned uy = __float_as_uint(y);
    ux = (ux + 0x7fffu + ((ux >> 16) & 1u)) >> 16;          // RNE
    uy = (uy + 0x7fffu + ((uy >> 16) & 1u)) & 0xffff0000u;  // RNE, keep high
    return ux | uy;
}

__device__ __forceinline__ float2 unpack_bf16x2(unsigned v) {
    float2 r;
    r.x = __uint_as_float(v << 16);
    r.y = __uint_as_float(v & 0xffff0000u);
    return r;
}

__device__ __forceinline__ unsigned short pack_fp8x2(float x, float y) {
    int v = __builtin_amdgcn_cvt_pk_fp8_f32(x, y, 0, false);   // low word
    return (unsigned short)(unsigned)v;
}

__device__ __forceinline__ float2 unpack_fp8x2(unsigned short v) {
    vf2 r = __builtin_amdgcn_cvt_pk_f32_fp8((int)(unsigned)v, false);
    float2 o;
    o.x = r[0];
    o.y = r[1];
    return o;
}

// ---------------- dtype probe ----------------
__global__ void k_detect(const int* __restrict__ p, int npairs, int* __restrict__ flag) {
    __shared__ int any32;
    if (threadIdx.x == 0) any32 = 0;
    __syncthreads();
    for (int i = threadIdx.x; i < npairs; i += blockDim.x)
        if (p[2 * i + 1] != 0) any32 = 1;
    __syncthreads();
    if (threadIdx.x == 0) *flag = any32 ? 0 : 1;   // 1 => int64
}

// ---------------- preprocessing ----------------

__global__ void k_zero_i32(int* __restrict__ p, int n) {
    int i = blockIdx.x * blockDim.x + threadIdx.x;
    if (i < n) p[i] = 0;
}

__global__ void k_count(const void* __restrict__ ei, int E, int* __restrict__ cnt,
                        const int* __restrict__ flag) {
    int is64 = *flag;
    int e = blockIdx.x * blockDim.x + threadIdx.x;
    if (e < E) {
        int d = idx_at(ei, (size_t)E + e, is64);
        atomicAdd(&cnt[d], 1);
    }
}

__global__ void k_dinv(const int* __restrict__ cnt, float* __restrict__ dinv, int N) {
    int i = blockIdx.x * blockDim.x + threadIdx.x;
    if (i < N) dinv[i] = rsqrtf((float)(cnt[i] + 1));
}

__global__ void k_scan1(const int* __restrict__ cnt, int* __restrict__ rp,
                        int* __restrict__ bsum, int N) {
    __shared__ int s[256];
    int t = threadIdx.x;
    int i = blockIdx.x * 256 + t;
    int v = (i < N) ? (cnt[i] + 1) : 0;   // +1 self-loop slot
    s[t] = v;
    __syncthreads();
    for (int off = 1; off < 256; off <<= 1) {
        int add = (t >= off) ? s[t - off] : 0;
        __syncthreads();
        s[t] += add;
        __syncthreads();
    }
    if (i < N) rp[i] = s[t] - v;
    if (t == 255) bsum[blockIdx.x] = s[255];
}

__global__ void k_scan2(int* __restrict__ bsum, int nb) {
    __shared__ int s[512];
    int t = threadIdx.x;
    int v = (t < nb) ? bsum[t] : 0;
    s[t] = v;
    __syncthreads();
    for (int off = 1; off < 512; off <<= 1) {
        int add = (t >= off) ? s[t - off] : 0;
        __syncthreads();
        s[t] += add;
        __syncthreads();
    }
    if (t < nb) bsum[t] = s[t] - v;
}

__global__ void k_scan3(int* __restrict__ rp, const int* __restrict__ bsum,
                        int* __restrict__ cursor, int* __restrict__ col,
                        int N, int Etot) {
    int i = blockIdx.x * blockDim.x + threadIdx.x;
    if (i < N) {
        int r = rp[i] + bsum[i >> 8];
        rp[i] = r;
        cursor[i] = 1;
        col[r] = i;          // self-loop first in each row (weightless)
    }
    if (i == 0) rp[N] = Etot;
}

// 4 edges per thread; no dinv gathers (weightless CSR).
__global__ __launch_bounds__(256) void k_place(const void* __restrict__ ei, int E,
                                               const int* __restrict__ rp,
                                               int* __restrict__ cursor,
                                               int* __restrict__ col,
                                               const int* __restrict__ flag) {
    const int is64 = *flag;
    const int e0 = (blockIdx.x * blockDim.x + threadIdx.x) * 4;
    if (e0 >= E) return;
    const int n = min(4, E - e0);
    int s[4], d[4];
#pragma unroll
    for (int k = 0; k < 4; ++k) {
        int e = e0 + min(k, n - 1);
        s[k] = idx_at(ei, (size_t)e, is64);
        d[k] = idx_at(ei, (size_t)E + e, is64);
    }
    int pos[4];
#pragma unroll
    for (int k = 0; k < 4; ++k)
        if (k < n) pos[k] = rp[d[k]] + atomicAdd(&cursor[d[k]], 1);
#pragma unroll
    for (int k = 0; k < 4; ++k)
        if (k < n) col[pos[k]] = s[k];
}

// ---------------- W transpose+cvt: Wt[c][k] = bf16(W[k][c]), W is [K][128] ----------------
__global__ void k_wt(const float* __restrict__ W, unsigned short* __restrict__ Wt, int K) {
    int i = blockIdx.x * blockDim.x + threadIdx.x;
    if (i < K * 128) {
        int k = i >> 7, c = i & 127;
        Wt[c * K + k] = bf16_of(W[i]);
    }
}

// ---------------- MFMA GEMM: y0 fp8 (= dinv*h) + alpha*h bf16 ----------------

template <int KTOT, bool AF32>
__global__ __launch_bounds__(256) void k_gemm_mfma(const void* __restrict__ Ap,
                                                   const unsigned short* __restrict__ Wt,
                                                   const float* __restrict__ dinv,
                                                   unsigned short* __restrict__ z0,
                                                   unsigned* __restrict__ ah, int N) {
    __shared__ __align__(16) char smem[64 * 132 * 4];
    unsigned short (*As)[40] = (unsigned short(*)[40])smem;            // 64 x 32 (+8 pad)
    unsigned short (*Bs)[40] = (unsigned short(*)[40])(smem + 5120);   // 128 x 32 (+8 pad), [col][k]
    float (*Cs)[132] = (float(*)[132])smem;

    const int t    = threadIdx.x;
    const int lane = t & 63;
    const int w    = t >> 6;
    const int wr   = w >> 1;
    const int wc   = w & 1;
    const int r0   = blockIdx.x * 64;

    f32x4 acc[2][4];
#pragma unroll
    for (int i = 0; i < 2; ++i)
#pragma unroll
        for (int j = 0; j < 4; ++j)
#pragma unroll
            for (int q = 0; q < 4; ++q) acc[i][j][q] = 0.f;

    const int arow = t >> 2;
    const int akc  = (t & 3) * 8;
    const int bcol = t >> 1;
    const int bkc  = (t & 1) * 16;

    for (int k0 = 0; k0 < KTOT; k0 += 32) {
        {
            int gr = r0 + arow;
            if (AF32) {
                uint4 s = make_uint4(0, 0, 0, 0);
                if (gr < N) {
                    const float* a = (const float*)Ap + (size_t)gr * KTOT + k0 + akc;
                    float4 v0 = *(const float4*)a;
                    float4 v1 = *(const float4*)(a + 4);
                    s.x = pack_bf16x2(v0.x, v0.y);
                    s.y = pack_bf16x2(v0.z, v0.w);
                    s.z = pack_bf16x2(v1.x, v1.y);
                    s.w = pack_bf16x2(v1.z, v1.w);
                }
                *(uint4*)&As[arow][akc] = s;
            } else {
                uint4 s = make_uint4(0, 0, 0, 0);
                if (gr < N) s = *(const uint4*)((const unsigned short*)Ap + (size_t)gr * KTOT + k0 + akc);
                *(uint4*)&As[arow][akc] = s;
            }
        }
        {
            const unsigned short* wsrc = Wt + (size_t)bcol * KTOT + k0 + bkc;
            *(uint4*)&Bs[bcol][bkc]     = *(const uint4*)wsrc;
            *(uint4*)&Bs[bcol][bkc + 8] = *(const uint4*)(wsrc + 8);
        }
        __syncthreads();
        {
            const int kblk = (lane >> 4) * 8;
            const int l15  = lane & 15;
            bf16x8 af[2], bfr[4];
#pragma unroll
            for (int i = 0; i < 2; ++i)
                af[i] = *(const bf16x8*)&As[wr * 32 + i * 16 + l15][kblk];
#pragma unroll
            for (int j = 0; j < 4; ++j)
                bfr[j] = *(const bf16x8*)&Bs[wc * 64 + j * 16 + l15][kblk];
#pragma unroll
            for (int i = 0; i < 2; ++i)
#pragma unroll
                for (int j = 0; j < 4; ++j)
                    acc[i][j] = __builtin_amdgcn_mfma_f32_16x16x32_bf16(af[i], bfr[j], acc[i][j], 0, 0, 0);
        }
        __syncthreads();
    }

    {
        const int l15 = lane & 15;
        const int rq  = (lane >> 4) * 4;
#pragma unroll
        for (int i = 0; i < 2; ++i)
#pragma unroll
            for (int j = 0; j < 4; ++j)
#pragma unroll
                for (int q = 0; q < 4; ++q)
                    Cs[wr * 32 + i * 16 + rq + q][wc * 64 + j * 16 + l15] = acc[i][j][q];
    }
    __syncthreads();
    {
        const int row = t >> 2;
        const int cb  = (t & 3) * 32;
        const int gr  = r0 + row;
        if (gr < N) {
            float dv = dinv[gr];
            float c[32];
#pragma unroll
            for (int m = 0; m < 8; ++m) {
                float4 v = *(const float4*)&Cs[row][cb + m * 4];
                c[m * 4 + 0] = v.x; c[m * 4 + 1] = v.y; c[m * 4 + 2] = v.z; c[m * 4 + 3] = v.w;
            }
            unsigned pk[8];
#pragma unroll
            for (int m = 0; m < 8; ++m) {
                unsigned lo = (unsigned)pack_fp8x2(dv * c[4 * m + 0], dv * c[4 * m + 1]);
                unsigned hi = (unsigned)pack_fp8x2(dv * c[4 * m + 2], dv * c[4 * m + 3]);
                pk[m] = lo | (hi << 16);
            }
            uint4* zd = (uint4*)&z0[((size_t)gr << 6) + (cb >> 1)];
            zd[0] = make_uint4(pk[0], pk[1], pk[2], pk[3]);
            zd[1] = make_uint4(pk[4], pk[5], pk[6], pk[7]);
            unsigned am[16];
#pragma unroll
            for (int m = 0; m < 16; ++m)
                am[m] = pack_bf16x2(A_ * c[2 * m], A_ * c[2 * m + 1]);
            uint4* ad = (uint4*)&ah[((size_t)gr << 6) + (cb >> 1)];
            ad[0] = make_uint4(am[0],  am[1],  am[2],  am[3]);
            ad[1] = make_uint4(am[4],  am[5],  am[6],  am[7]);
            ad[2] = make_uint4(am[8],  am[9],  am[10], am[11]);
            ad[3] = make_uint4(am[12], am[13], am[14], am[15]);
        }
    }
}

// ---------------- propagation hop (weightless gather of y rows) ----------------
// z_next = 0.9*dinv[d]*S + 0.1h, S = sum y[src] (incl self); y_next = dinv*z_next.
// OUTM: 0 = fp8 y, 1 = bf16 z, 3 = relu+bf16 z.

template <int B>
__device__ __forceinline__ void hop_batch(const unsigned short* __restrict__ yb,
                                          const int* __restrict__ col,
                                          int e, int lane,
                                          float& ax, float& ay,
                                          float& bx, float& by) {
    int c[B];
#pragma unroll
    for (int k = 0; k < B; ++k) c[k] = col[e + k];
    unsigned short v[B];
#pragma unroll
    for (int k = 0; k < B; ++k) v[k] = yb[((unsigned)c[k] << 6) + lane];
#pragma unroll
    for (int k = 0; k < B; ++k) {
        float2 z = unpack_fp8x2(v[k]);
        if (k & 1) { bx += z.x; by += z.y; }
        else       { ax += z.x; ay += z.y; }
    }
}

template <int OUTM>
__global__ __launch_bounds__(256) void k_hop(const unsigned short* __restrict__ yin,
                                             const unsigned* __restrict__ ah,
                                             const float* __restrict__ dinv,
                                             void* __restrict__ zout,
                                             const int* __restrict__ rp,
                                             const int* __restrict__ col, int N) {
    int wid  = (blockIdx.x * blockDim.x + threadIdx.x) >> 6;
    int lane = threadIdx.x & 63;
    if (wid >= N) return;

    int e   = __builtin_amdgcn_readfirstlane(rp[wid]);
    int end = __builtin_amdgcn_readfirstlane(rp[wid + 1]);
    float dv = dinv[wid];

    float2 hh = unpack_bf16x2(ah[((size_t)wid << 6) + lane]);

    float ax = 0.f, ay = 0.f, bx = 0.f, by = 0.f;

    for (; e + 16 <= end; e += 16)
        hop_batch<16>(yin, col, e, lane, ax, ay, bx, by);
    if (e + 8 <= end) { hop_batch<8>(yin, col, e, lane, ax, ay, bx, by); e += 8; }
    if (e + 4 <= end) { hop_batch<4>(yin, col, e, lane, ax, ay, bx, by); e += 4; }
    for (; e < end; ++e) {
        float2 z = unpack_fp8x2(yin[((unsigned)col[e] << 6) + lane]);
        ax += z.x; ay += z.y;
    }

    float q  = OMA * dv;
    float ox = q * (ax + bx) + hh.x;   // = z_next
    float oy = q * (ay + by) + hh.y;
    if (OUTM == 0) {
        ((unsigned short*)zout)[((size_t)wid << 6) + lane] = pack_fp8x2(dv * ox, dv * oy);
    } else if (OUTM == 1) {
        ((unsigned*)zout)[((size_t)wid << 6) + lane] = pack_bf16x2(ox, oy);
    } else {
        ((unsigned*)zout)[((size_t)wid << 6) + lane] =
            pack_bf16x2(fmaxf(ox, 0.f), fmaxf(oy, 0.f));
    }
}

// ---------------- decode: out[j] = dot(z[e0[j]], z[e1[j]]), z bf16 ----------------

__global__ __launch_bounds__(256) void k_decode(const unsigned* __restrict__ z,
                                                const void* __restrict__ pos,
                                                const void* __restrict__ neg,
                                                float* __restrict__ out, int P, int Q,
                                                const int* __restrict__ flag) {
    int is64 = *flag;
    int t   = blockIdx.x * blockDim.x + threadIdx.x;
    int j   = t >> 4;
    int sub = t & 15;
    if (j >= P + Q) return;
    int a, b;
    if (j < P) { a = idx_at(pos, (size_t)j, is64); b = idx_at(pos, (size_t)P + j, is64); }
    else       { int jj = j - P; a = idx_at(neg, (size_t)jj, is64); b = idx_at(neg, (size_t)Q + jj, is64); }
    const uint4* za = (const uint4*)&z[(size_t)a << 6];
    const uint4* zb = (const uint4*)&z[(size_t)b << 6];
    uint4 va = za[sub];
    uint4 vb = zb[sub];
    float s = 0.f;
    {
        float2 xa, xb;
        xa = unpack_bf16x2(va.x); xb = unpack_bf16x2(vb.x);
        s += xa.x * xb.x + xa.y * xb.y;
        xa = unpack_bf16x2(va.y); xb = unpack_bf16x2(vb.y);
        s += xa.x * xb.x + xa.y * xb.y;
        xa = unpack_bf16x2(va.z); xb = unpack_bf16x2(vb.z);
        s += xa.x * xb.x + xa.y * xb.y;
        xa = unpack_bf16x2(va.w); xb = unpack_bf16x2(vb.w);
        s += xa.x * xb.x + xa.y * xb.y;
    }
#pragma unroll
    for (int off = 8; off >= 1; off >>= 1) s += __shfl_xor(s, off, 16);
    if (sub == 0) out[j] = s;
}

// ---------------- launch ----------------

extern "C" void kernel_launch(void* const* d_in, const int* in_sizes, int n_in,
                              void* d_out, int out_size, void* d_ws, size_t ws_size,
                              hipStream_t stream) {
    const float* x   = (const float*)d_in[0];
    const void*  ei  = d_in[1];
    const void*  pos = d_in[2];
    const void*  neg = d_in[3];
    const float* W1  = (const float*)d_in[4];
    const float* W2  = (const float*)d_in[5];
    float*       out = (float*)d_out;

    const int N = in_sizes[0] / Fin;
    const int E = in_sizes[1] / 2;
    const int P = in_sizes[2] / 2;
    const int Q = in_sizes[3] / 2;
    const int Etot = E + N;

    char*  ws  = (char*)d_ws;
    size_t off = 0;
    auto carve = [&](size_t bytes) -> void* {
        void* p = ws + off;
        off = (off + bytes + 511) & ~(size_t)511;
        return p;
    };
    unsigned short* f0   = (unsigned short*)carve((size_t)N * 64 * 2);
    unsigned short* f1   = (unsigned short*)carve((size_t)N * 64 * 2);
    unsigned*       zB2  = (unsigned*)carve((size_t)N * 64 * 4);   // bf16 final (decode)
    unsigned*       zRB  = (unsigned*)carve((size_t)N * 64 * 4);   // relu bf16 (L2 GEMM A)
    unsigned*       ah   = (unsigned*)carve((size_t)N * 64 * 4);
    unsigned short* Wt1  = (unsigned short*)carve((size_t)128 * 256 * 2);
    unsigned short* Wt2  = (unsigned short*)carve((size_t)128 * 128 * 2);
    float*          dinv = (float*)carve((size_t)N * 4);
    int*     cnt    = (int*)carve((size_t)N * 4);
    int*     rp     = (int*)carve((size_t)(N + 1) * 4);
    int*     cursor = (int*)carve((size_t)N * 4);
    int*     col    = (int*)carve((size_t)Etot * 4);
    int      nb     = (N + 255) / 256;
    int*     bsum   = (int*)carve((size_t)nb * 4);
    int*     flag   = (int*)carve(4);
    (void)ws_size;

    const int gN = (N + 255) / 256;
    const int gE = (E + 255) / 256;

    k_detect<<<1, 256, 0, stream>>>((const int*)ei, 4096, flag);
    k_zero_i32<<<gN, 256, 0, stream>>>(cnt, N);
    k_count<<<gE, 256, 0, stream>>>(ei, E, cnt, flag);
    k_dinv<<<gN, 256, 0, stream>>>(cnt, dinv, N);
    k_scan1<<<nb, 256, 0, stream>>>(cnt, rp, bsum, N);
    k_scan2<<<1, 512, 0, stream>>>(bsum, nb);
    k_scan3<<<gN, 256, 0, stream>>>(rp, bsum, cursor, col, N, Etot);
    k_place<<<(E + 1023) / 1024, 256, 0, stream>>>(ei, E, rp, cursor, col, flag);
    k_wt<<<(256 * 128 + 255) / 256, 256, 0, stream>>>(W1, Wt1, Fin);
    k_wt<<<(128 * 128 + 255) / 256, 256, 0, stream>>>(W2, Wt2, Hd);

    const int gGemm = (N + 63) / 64;
    const int gHop  = (N * 64 + 255) / 256;

    unsigned short* fb[2] = {f0, f1};

    // ---- layer 1: GEMM(y0 fp8 + ah) -> 9 fp8 hops -> final hop writes relu-bf16 z ----
    k_gemm_mfma<Fin, true><<<gGemm, 256, 0, stream>>>(x, Wt1, dinv, f0, ah, N);
    for (int k = 0; k < 9; ++k)
        k_hop<0><<<gHop, 256, 0, stream>>>(fb[k & 1], ah, dinv, fb[(k + 1) & 1], rp, col, N);
    k_hop<3><<<gHop, 256, 0, stream>>>(f1, ah, dinv, zRB, rp, col, N);

    // ---- layer 2: GEMM -> 9 fp8 hops -> final hop writes bf16 z ----
    k_gemm_mfma<Hd, false><<<gGemm, 256, 0, stream>>>(zRB, Wt2, dinv, f0, ah, N);
    for (int k = 0; k < 9; ++k)
        k_hop<0><<<gHop, 256, 0, stream>>>(fb[k & 1], ah, dinv, fb[(k + 1) & 1], rp, col, N);
    k_hop<1><<<gHop, 256, 0, stream>>>(f1, ah, dinv, zB2, rp, col, N);

    // ---- decode (bf16 z) ----
    const int gDec = ((P + Q) * 16 + 255) / 256;
    k_decode<<<gDec, 256, 0, stream>>>(zB2, pos, neg, out, P, Q, flag);
}

// Round 13
// 1037.303 us; speedup vs baseline: 1.0141x; 1.0049x over previous
//
#include <hip/hip_runtime.h>

// APPNP link-prediction: N=100000, F=256, H=128, E=1.6M, K=10 x 2 layers.
// Weightless CSR-by-dst (y = dinv*z trick), fp8 e4m3 hop storage (128B rows),
// MFMA bf16 GEMMs. CSR build uses two-phase BINNED placement: bin edges by
// dst/384 (coalesced runs), then one workgroup per bin scatters into its
// ~25KB cw window with an LDS cursor -> full-line writebacks.

constexpr int Hd = 128;
constexpr int Fin = 256;
constexpr float A_ = 0.1f;
constexpr float OMA = 0.9f;
constexpr int BSZ = 384;     // nodes per bin (<=1024 bins for N<=393K)

typedef float vf2 __attribute__((ext_vector_type(2)));
typedef __bf16 bf16x8 __attribute__((ext_vector_type(8)));
typedef float f32x4 __attribute__((ext_vector_type(4)));

__device__ __forceinline__ int idx_at(const void* p, size_t i, int is64) {
    if (is64) return (int)((const long long*)p)[i];
    return ((const int*)p)[i];
}

__device__ __forceinline__ unsigned short bf16_of(float x) {
    unsigned u = __float_as_uint(x);
    return (unsigned short)((u + 0x7fffu + ((u >> 16) & 1u)) >> 16);
}

__device__ __forceinline__ unsigned pack_bf16x2(float x, float y) {
    unsigned ux = __float_as_uint(x);
    unsigned uy = __float_as_uint(y);
    ux = (ux + 0x7fffu + ((ux >> 16) & 1u)) >> 16;          // RNE
    uy = (uy + 0x7fffu + ((uy >> 16) & 1u)) & 0xffff0000u;  // RNE, keep high
    return ux | uy;
}

__device__ __forceinline__ float2 unpack_bf16x2(unsigned v) {
    float2 r;
    r.x = __uint_as_float(v << 16);
    r.y = __uint_as_float(v & 0xffff0000u);
    return r;
}

__device__ __forceinline__ unsigned short pack_fp8x2(float x, float y) {
    int v = __builtin_amdgcn_cvt_pk_fp8_f32(x, y, 0, false);   // low word
    return (unsigned short)(unsigned)v;
}

__device__ __forceinline__ float2 unpack_fp8x2(unsigned short v) {
    vf2 r = __builtin_amdgcn_cvt_pk_f32_fp8((int)(unsigned)v, false);
    float2 o;
    o.x = r[0];
    o.y = r[1];
    return o;
}

// ---------------- dtype probe ----------------
__global__ void k_detect(const int* __restrict__ p, int npairs, int* __restrict__ flag) {
    __shared__ int any32;
    if (threadIdx.x == 0) any32 = 0;
    __syncthreads();
    for (int i = threadIdx.x; i < npairs; i += blockDim.x)
        if (p[2 * i + 1] != 0) any32 = 1;
    __syncthreads();
    if (threadIdx.x == 0) *flag = any32 ? 0 : 1;   // 1 => int64
}

// ---------------- preprocessing ----------------

__global__ void k_zero_i32(int* __restrict__ p, int n) {
    int i = blockIdx.x * blockDim.x + threadIdx.x;
    if (i < n) p[i] = 0;
}

__global__ void k_count(const void* __restrict__ ei, int E, int* __restrict__ cnt,
                        const int* __restrict__ flag) {
    int is64 = *flag;
    int e = blockIdx.x * blockDim.x + threadIdx.x;
    if (e < E) {
        int d = idx_at(ei, (size_t)E + e, is64);
        atomicAdd(&cnt[d], 1);
    }
}

__global__ void k_dinv(const int* __restrict__ cnt, float* __restrict__ dinv, int N) {
    int i = blockIdx.x * blockDim.x + threadIdx.x;
    if (i < N) dinv[i] = rsqrtf((float)(cnt[i] + 1));
}

__global__ void k_scan1(const int* __restrict__ cnt, int* __restrict__ rp,
                        int* __restrict__ bsum, int N) {
    __shared__ int s[256];
    int t = threadIdx.x;
    int i = blockIdx.x * 256 + t;
    int v = (i < N) ? (cnt[i] + 1) : 0;   // +1 self-loop slot
    s[t] = v;
    __syncthreads();
    for (int off = 1; off < 256; off <<= 1) {
        int add = (t >= off) ? s[t - off] : 0;
        __syncthreads();
        s[t] += add;
        __syncthreads();
    }
    if (i < N) rp[i] = s[t] - v;
    if (t == 255) bsum[blockIdx.x] = s[255];
}

__global__ void k_scan2(int* __restrict__ bsum, int nb) {
    __shared__ int s[512];
    int t = threadIdx.x;
    int v = (t < nb) ? bsum[t] : 0;
    s[t] = v;
    __syncthreads();
    for (int off = 1; off < 512; off <<= 1) {
        int add = (t >= off) ? s[t - off] : 0;
        __syncthreads();
        s[t] += add;
        __syncthreads();
    }
    if (t < nb) bsum[t] = s[t] - v;
}

__global__ void k_scan3(int* __restrict__ rp, const int* __restrict__ bsum,
                        int* __restrict__ col, int N, int Etot) {
    int i = blockIdx.x * blockDim.x + threadIdx.x;
    if (i < N) {
        int r = rp[i] + bsum[i >> 8];
        rp[i] = r;
        col[r] = i;          // self-loop first in each row (weightless)
    }
    if (i == 0) rp[N] = Etot;
}

// ---------------- binned two-phase placement ----------------

// bin histogram (dst/BSZ) -> bcnt[nbk]
__global__ __launch_bounds__(256) void k_bhist(const void* __restrict__ ei, int E,
                                               int* __restrict__ bcnt,
                                               const int* __restrict__ flag, int nbk) {
    __shared__ int h[1024];
    int is64 = *flag;
    for (int i = threadIdx.x; i < nbk; i += 256) h[i] = 0;
    __syncthreads();
    for (int e = blockIdx.x * 256 + threadIdx.x; e < E; e += gridDim.x * 256) {
        int d = idx_at(ei, (size_t)E + e, is64);
        atomicAdd(&h[d / BSZ], 1);
    }
    __syncthreads();
    for (int i = threadIdx.x; i < nbk; i += 256)
        if (h[i]) atomicAdd(&bcnt[i], h[i]);
}

// exclusive scan of bcnt -> bbase[nbk+1], gcur
__global__ void k_bscan(const int* __restrict__ bcnt, int* __restrict__ bbase,
                        int* __restrict__ gcur, int nbk, int E) {
    __shared__ int s[1024];
    int t = threadIdx.x;
    int v = (t < nbk) ? bcnt[t] : 0;
    s[t] = v;
    __syncthreads();
    for (int off = 1; off < 1024; off <<= 1) {
        int add = (t >= off) ? s[t - off] : 0;
        __syncthreads();
        s[t] += add;
        __syncthreads();
    }
    if (t < nbk) {
        bbase[t] = s[t] - v;
        gcur[t]  = s[t] - v;
    }
    if (t == 0) bbase[nbk] = E;
}

// phase A: bin edges into tmp (bin-contiguous, per-block runs)
__global__ __launch_bounds__(256) void k_binA(const void* __restrict__ ei, int E,
                                              int* __restrict__ gcur,
                                              int2* __restrict__ tmp,
                                              const int* __restrict__ flag, int nbk) {
    __shared__ int hA[1024], hB[1024], sbase[1024];
    int is64 = *flag;
    for (int i = threadIdx.x; i < nbk; i += 256) { hA[i] = 0; hB[i] = 0; }
    __syncthreads();
    const int e0 = (blockIdx.x * 256 + threadIdx.x) * 4;
    int s[4], d[4], b[4];
    const int n = (e0 < E) ? min(4, E - e0) : 0;
#pragma unroll
    for (int k = 0; k < 4; ++k)
        if (k < n) {
            s[k] = idx_at(ei, (size_t)(e0 + k), is64);
            d[k] = idx_at(ei, (size_t)E + (e0 + k), is64);
            b[k] = d[k] / BSZ;
            atomicAdd(&hA[b[k]], 1);
        }
    __syncthreads();
    for (int i = threadIdx.x; i < nbk; i += 256)
        sbase[i] = hA[i] ? atomicAdd(&gcur[i], hA[i]) : 0;
    __syncthreads();
#pragma unroll
    for (int k = 0; k < 4; ++k)
        if (k < n) {
            int off = atomicAdd(&hB[b[k]], 1);
            int2 p;
            p.x = s[k];
            p.y = d[k];
            tmp[sbase[b[k]] + off] = p;
        }
}

// phase B: one workgroup per bin; LDS cursor; scatter into local cw window
__global__ __launch_bounds__(256) void k_binB(const int2* __restrict__ tmp,
                                              const int* __restrict__ bbase,
                                              const int* __restrict__ rp,
                                              int* __restrict__ col, int N) {
    __shared__ int lcur[BSZ];
    const int b  = blockIdx.x;
    const int lo = b * BSZ;
    const int cnt = min(BSZ, N - lo);
    for (int i = threadIdx.x; i < cnt; i += 256) lcur[i] = 1;   // slot 0 = self-loop
    __syncthreads();
    const int start = bbase[b], end = bbase[b + 1];
    for (int i = start + threadIdx.x; i < end; i += 256) {
        int2 p = tmp[i];
        int off = atomicAdd(&lcur[p.y - lo], 1);
        col[rp[p.y] + off] = p.x;
    }
}

// ---------------- W transpose+cvt: Wt[c][k] = bf16(W[k][c]), W is [K][128] ----------------
__global__ void k_wt(const float* __restrict__ W, unsigned short* __restrict__ Wt, int K) {
    int i = blockIdx.x * blockDim.x + threadIdx.x;
    if (i < K * 128) {
        int k = i >> 7, c = i & 127;
        Wt[c * K + k] = bf16_of(W[i]);
    }
}

// ---------------- MFMA GEMM: y0 fp8 (= dinv*h) + alpha*h bf16 ----------------

template <int KTOT, bool AF32>
__global__ __launch_bounds__(256) void k_gemm_mfma(const void* __restrict__ Ap,
                                                   const unsigned short* __restrict__ Wt,
                                                   const float* __restrict__ dinv,
                                                   unsigned short* __restrict__ z0,
                                                   unsigned* __restrict__ ah, int N) {
    __shared__ __align__(16) char smem[64 * 132 * 4];
    unsigned short (*As)[40] = (unsigned short(*)[40])smem;            // 64 x 32 (+8 pad)
    unsigned short (*Bs)[40] = (unsigned short(*)[40])(smem + 5120);   // 128 x 32 (+8 pad), [col][k]
    float (*Cs)[132] = (float(*)[132])smem;

    const int t    = threadIdx.x;
    const int lane = t & 63;
    const int w    = t >> 6;
    const int wr   = w >> 1;
    const int wc   = w & 1;
    const int r0   = blockIdx.x * 64;

    f32x4 acc[2][4];
#pragma unroll
    for (int i = 0; i < 2; ++i)
#pragma unroll
        for (int j = 0; j < 4; ++j)
#pragma unroll
            for (int q = 0; q < 4; ++q) acc[i][j][q] = 0.f;

    const int arow = t >> 2;
    const int akc  = (t & 3) * 8;
    const int bcol = t >> 1;
    const int bkc  = (t & 1) * 16;

    for (int k0 = 0; k0 < KTOT; k0 += 32) {
        {
            int gr = r0 + arow;
            if (AF32) {
                uint4 s = make_uint4(0, 0, 0, 0);
                if (gr < N) {
                    const float* a = (const float*)Ap + (size_t)gr * KTOT + k0 + akc;
                    float4 v0 = *(const float4*)a;
                    float4 v1 = *(const float4*)(a + 4);
                    s.x = pack_bf16x2(v0.x, v0.y);
                    s.y = pack_bf16x2(v0.z, v0.w);
                    s.z = pack_bf16x2(v1.x, v1.y);
                    s.w = pack_bf16x2(v1.z, v1.w);
                }
                *(uint4*)&As[arow][akc] = s;
            } else {
                uint4 s = make_uint4(0, 0, 0, 0);
                if (gr < N) s = *(const uint4*)((const unsigned short*)Ap + (size_t)gr * KTOT + k0 + akc);
                *(uint4*)&As[arow][akc] = s;
            }
        }
        {
            const unsigned short* wsrc = Wt + (size_t)bcol * KTOT + k0 + bkc;
            *(uint4*)&Bs[bcol][bkc]     = *(const uint4*)wsrc;
            *(uint4*)&Bs[bcol][bkc + 8] = *(const uint4*)(wsrc + 8);
        }
        __syncthreads();
        {
            const int kblk = (lane >> 4) * 8;
            const int l15  = lane & 15;
            bf16x8 af[2], bfr[4];
#pragma unroll
            for (int i = 0; i < 2; ++i)
                af[i] = *(const bf16x8*)&As[wr * 32 + i * 16 + l15][kblk];
#pragma unroll
            for (int j = 0; j < 4; ++j)
                bfr[j] = *(const bf16x8*)&Bs[wc * 64 + j * 16 + l15][kblk];
#pragma unroll
            for (int i = 0; i < 2; ++i)
#pragma unroll
                for (int j = 0; j < 4; ++j)
                    acc[i][j] = __builtin_amdgcn_mfma_f32_16x16x32_bf16(af[i], bfr[j], acc[i][j], 0, 0, 0);
        }
        __syncthreads();
    }

    {
        const int l15 = lane & 15;
        const int rq  = (lane >> 4) * 4;
#pragma unroll
        for (int i = 0; i < 2; ++i)
#pragma unroll
            for (int j = 0; j < 4; ++j)
#pragma unroll
                for (int q = 0; q < 4; ++q)
                    Cs[wr * 32 + i * 16 + rq + q][wc * 64 + j * 16 + l15] = acc[i][j][q];
    }
    __syncthreads();
    {
        const int row = t >> 2;
        const int cb  = (t & 3) * 32;
        const int gr  = r0 + row;
        if (gr < N) {
            float dv = dinv[gr];
            float c[32];
#pragma unroll
            for (int m = 0; m < 8; ++m) {
                float4 v = *(const float4*)&Cs[row][cb + m * 4];
                c[m * 4 + 0] = v.x; c[m * 4 + 1] = v.y; c[m * 4 + 2] = v.z; c[m * 4 + 3] = v.w;
            }
            unsigned pk[8];
#pragma unroll
            for (int m = 0; m < 8; ++m) {
                unsigned lo = (unsigned)pack_fp8x2(dv * c[4 * m + 0], dv * c[4 * m + 1]);
                unsigned hi = (unsigned)pack_fp8x2(dv * c[4 * m + 2], dv * c[4 * m + 3]);
                pk[m] = lo | (hi << 16);
            }
            uint4* zd = (uint4*)&z0[((size_t)gr << 6) + (cb >> 1)];
            zd[0] = make_uint4(pk[0], pk[1], pk[2], pk[3]);
            zd[1] = make_uint4(pk[4], pk[5], pk[6], pk[7]);
            unsigned am[16];
#pragma unroll
            for (int m = 0; m < 16; ++m)
                am[m] = pack_bf16x2(A_ * c[2 * m], A_ * c[2 * m + 1]);
            uint4* ad = (uint4*)&ah[((size_t)gr << 6) + (cb >> 1)];
            ad[0] = make_uint4(am[0],  am[1],  am[2],  am[3]);
            ad[1] = make_uint4(am[4],  am[5],  am[6],  am[7]);
            ad[2] = make_uint4(am[8],  am[9],  am[10], am[11]);
            ad[3] = make_uint4(am[12], am[13], am[14], am[15]);
        }
    }
}

// ---------------- propagation hop (weightless gather of y rows) ----------------
// z_next = 0.9*dinv[d]*S + 0.1h, S = sum y[src] (incl self); y_next = dinv*z_next.
// OUTM: 0 = fp8 y, 1 = bf16 z, 3 = relu+bf16 z.

template <int B>
__device__ __forceinline__ void hop_batch(const unsigned short* __restrict__ yb,
                                          const int* __restrict__ col,
                                          int e, int lane,
                                          float& ax, float& ay,
                                          float& bx, float& by) {
    int c[B];
#pragma unroll
    for (int k = 0; k < B; ++k) c[k] = col[e + k];
    unsigned short v[B];
#pragma unroll
    for (int k = 0; k < B; ++k) v[k] = yb[((unsigned)c[k] << 6) + lane];
#pragma unroll
    for (int k = 0; k < B; ++k) {
        float2 z = unpack_fp8x2(v[k]);
        if (k & 1) { bx += z.x; by += z.y; }
        else       { ax += z.x; ay += z.y; }
    }
}

template <int OUTM>
__global__ __launch_bounds__(256) void k_hop(const unsigned short* __restrict__ yin,
                                             const unsigned* __restrict__ ah,
                                             const float* __restrict__ dinv,
                                             void* __restrict__ zout,
                                             const int* __restrict__ rp,
                                             const int* __restrict__ col, int N) {
    int wid  = (blockIdx.x * blockDim.x + threadIdx.x) >> 6;
    int lane = threadIdx.x & 63;
    if (wid >= N) return;

    int e   = __builtin_amdgcn_readfirstlane(rp[wid]);
    int end = __builtin_amdgcn_readfirstlane(rp[wid + 1]);
    float dv = dinv[wid];

    float2 hh = unpack_bf16x2(ah[((size_t)wid << 6) + lane]);

    float ax = 0.f, ay = 0.f, bx = 0.f, by = 0.f;

    for (; e + 16 <= end; e += 16)
        hop_batch<16>(yin, col, e, lane, ax, ay, bx, by);
    if (e + 8 <= end) { hop_batch<8>(yin, col, e, lane, ax, ay, bx, by); e += 8; }
    if (e + 4 <= end) { hop_batch<4>(yin, col, e, lane, ax, ay, bx, by); e += 4; }
    for (; e < end; ++e) {
        float2 z = unpack_fp8x2(yin[((unsigned)col[e] << 6) + lane]);
        ax += z.x; ay += z.y;
    }

    float q  = OMA * dv;
    float ox = q * (ax + bx) + hh.x;   // = z_next
    float oy = q * (ay + by) + hh.y;
    if (OUTM == 0) {
        ((unsigned short*)zout)[((size_t)wid << 6) + lane] = pack_fp8x2(dv * ox, dv * oy);
    } else if (OUTM == 1) {
        ((unsigned*)zout)[((size_t)wid << 6) + lane] = pack_bf16x2(ox, oy);
    } else {
        ((unsigned*)zout)[((size_t)wid << 6) + lane] =
            pack_bf16x2(fmaxf(ox, 0.f), fmaxf(oy, 0.f));
    }
}

// ---------------- decode: out[j] = dot(z[e0[j]], z[e1[j]]), z bf16 ----------------

__global__ __launch_bounds__(256) void k_decode(const unsigned* __restrict__ z,
                                                const void* __restrict__ pos,
                                                const void* __restrict__ neg,
                                                float* __restrict__ out, int P, int Q,
                                                const int* __restrict__ flag) {
    int is64 = *flag;
    int t   = blockIdx.x * blockDim.x + threadIdx.x;
    int j   = t >> 4;
    int sub = t & 15;
    if (j >= P + Q) return;
    int a, b;
    if (j < P) { a = idx_at(pos, (size_t)j, is64); b = idx_at(pos, (size_t)P + j, is64); }
    else       { int jj = j - P; a = idx_at(neg, (size_t)jj, is64); b = idx_at(neg, (size_t)Q + jj, is64); }
    const uint4* za = (const uint4*)&z[(size_t)a << 6];
    const uint4* zb = (const uint4*)&z[(size_t)b << 6];
    uint4 va = za[sub];
    uint4 vb = zb[sub];
    float s = 0.f;
    {
        float2 xa, xb;
        xa = unpack_bf16x2(va.x); xb = unpack_bf16x2(vb.x);
        s += xa.x * xb.x + xa.y * xb.y;
        xa = unpack_bf16x2(va.y); xb = unpack_bf16x2(vb.y);
        s += xa.x * xb.x + xa.y * xb.y;
        xa = unpack_bf16x2(va.z); xb = unpack_bf16x2(vb.z);
        s += xa.x * xb.x + xa.y * xb.y;
        xa = unpack_bf16x2(va.w); xb = unpack_bf16x2(vb.w);
        s += xa.x * xb.x + xa.y * xb.y;
    }
#pragma unroll
    for (int off = 8; off >= 1; off >>= 1) s += __shfl_xor(s, off, 16);
    if (sub == 0) out[j] = s;
}

// ---------------- launch ----------------

extern "C" void kernel_launch(void* const* d_in, const int* in_sizes, int n_in,
                              void* d_out, int out_size, void* d_ws, size_t ws_size,
                              hipStream_t stream) {
    const float* x   = (const float*)d_in[0];
    const void*  ei  = d_in[1];
    const void*  pos = d_in[2];
    const void*  neg = d_in[3];
    const float* W1  = (const float*)d_in[4];
    const float* W2  = (const float*)d_in[5];
    float*       out = (float*)d_out;

    const int N = in_sizes[0] / Fin;
    const int E = in_sizes[1] / 2;
    const int P = in_sizes[2] / 2;
    const int Q = in_sizes[3] / 2;
    const int Etot = E + N;
    const int nbk  = (N + BSZ - 1) / BSZ;   // 261 for N=100000 (cap 1024)

    char*  ws  = (char*)d_ws;
    size_t off = 0;
    auto carve = [&](size_t bytes) -> void* {
        void* p = ws + off;
        off = (off + bytes + 511) & ~(size_t)511;
        return p;
    };
    unsigned short* f0   = (unsigned short*)carve((size_t)N * 64 * 2);
    unsigned short* f1   = (unsigned short*)carve((size_t)N * 64 * 2);
    unsigned*       zB2  = (unsigned*)carve((size_t)N * 64 * 4);   // bf16 final (decode)
    unsigned*       zRB  = (unsigned*)carve((size_t)N * 64 * 4);   // relu bf16 (L2 GEMM A)
    unsigned*       ah   = (unsigned*)carve((size_t)N * 64 * 4);
    unsigned short* Wt1  = (unsigned short*)carve((size_t)128 * 256 * 2);
    unsigned short* Wt2  = (unsigned short*)carve((size_t)128 * 128 * 2);
    float*          dinv = (float*)carve((size_t)N * 4);
    int*     cnt    = (int*)carve((size_t)N * 4);
    int*     rp     = (int*)carve((size_t)(N + 1) * 4);
    int*     col    = (int*)carve((size_t)Etot * 4);
    int2*    tmp    = (int2*)carve((size_t)E * 8);
    int*     bcnt   = (int*)carve((size_t)nbk * 4);
    int*     bbase  = (int*)carve((size_t)(nbk + 1) * 4);
    int*     gcur   = (int*)carve((size_t)nbk * 4);
    int      nb     = (N + 255) / 256;
    int*     bsum   = (int*)carve((size_t)nb * 4);
    int*     flag   = (int*)carve(4);
    (void)ws_size;

    const int gN = (N + 255) / 256;
    const int gE = (E + 255) / 256;

    k_detect<<<1, 256, 0, stream>>>((const int*)ei, 4096, flag);
    k_zero_i32<<<gN, 256, 0, stream>>>(cnt, N);
    k_zero_i32<<<(nbk + 255) / 256, 256, 0, stream>>>(bcnt, nbk);
    k_count<<<gE, 256, 0, stream>>>(ei, E, cnt, flag);
    k_dinv<<<gN, 256, 0, stream>>>(cnt, dinv, N);
    k_scan1<<<nb, 256, 0, stream>>>(cnt, rp, bsum, N);
    k_scan2<<<1, 512, 0, stream>>>(bsum, nb);
    k_scan3<<<gN, 256, 0, stream>>>(rp, bsum, col, N, Etot);
    // binned placement
    k_bhist<<<512, 256, 0, stream>>>(ei, E, bcnt, flag, nbk);
    k_bscan<<<1, 1024, 0, stream>>>(bcnt, bbase, gcur, nbk, E);
    k_binA<<<(E + 1023) / 1024, 256, 0, stream>>>(ei, E, gcur, tmp, flag, nbk);
    k_binB<<<nbk, 256, 0, stream>>>(tmp, bbase, rp, col, N);
    k_wt<<<(256 * 128 + 255) / 256, 256, 0, stream>>>(W1, Wt1, Fin);
    k_wt<<<(128 * 128 + 255) / 256, 256, 0, stream>>>(W2, Wt2, Hd);

    const int gGemm = (N + 63) / 64;
    const int gHop  = (N * 64 + 255) / 256;

    unsigned short* fb[2] = {f0, f1};

    // ---- layer 1: GEMM(y0 fp8 + ah) -> 9 fp8 hops -> final hop writes relu-bf16 z ----
    k_gemm_mfma<Fin, true><<<gGemm, 256, 0, stream>>>(x, Wt1, dinv, f0, ah, N);
    for (int k = 0; k < 9; ++k)
        k_hop<0><<<gHop, 256, 0, stream>>>(fb[k & 1], ah, dinv, fb[(k + 1) & 1], rp, col, N);
    k_hop<3><<<gHop, 256, 0, stream>>>(f1, ah, dinv, zRB, rp, col, N);

    // ---- layer 2: GEMM -> 9 fp8 hops -> final hop writes bf16 z ----
    k_gemm_mfma<Hd, false><<<gGemm, 256, 0, stream>>>(zRB, Wt2, dinv, f0, ah, N);
    for (int k = 0; k < 9; ++k)
        k_hop<0><<<gHop, 256, 0, stream>>>(fb[k & 1], ah, dinv, fb[(k + 1) & 1], rp, col, N);
    k_hop<1><<<gHop, 256, 0, stream>>>(f1, ah, dinv, zB2, rp, col, N);

    // ---- decode (bf16 z) ----
    const int gDec = ((P + Q) * 16 + 255) / 256;
    k_decode<<<gDec, 256, 0, stream>>>(zB2, pos, neg, out, P, Q, flag);
}

// Round 14
// 974.948 us; speedup vs baseline: 1.0789x; 1.0640x over previous
//
#include <hip/hip_runtime.h>

// APPNP link-prediction: N=100000, F=256, H=128, E=1.6M, K=10 x 2 layers.
// Weightless CSR-by-dst (y = dinv*z trick), fp8 e4m3 hop storage (128B rows),
// MFMA bf16 GEMMs. CSR build fully binned: edges partitioned by dst/384 into
// tmp (coalesced), then per-bin LDS counting (k_bincnt, no random atomics)
// and per-bin scatter (k_binB, full-line writebacks).

constexpr int Hd = 128;
constexpr int Fin = 256;
constexpr float A_ = 0.1f;
constexpr float OMA = 0.9f;
constexpr int BSZ = 384;     // nodes per bin (<=1024 bins for N<=393K)

typedef float vf2 __attribute__((ext_vector_type(2)));
typedef __bf16 bf16x8 __attribute__((ext_vector_type(8)));
typedef float f32x4 __attribute__((ext_vector_type(4)));

__device__ __forceinline__ int idx_at(const void* p, size_t i, int is64) {
    if (is64) return (int)((const long long*)p)[i];
    return ((const int*)p)[i];
}

__device__ __forceinline__ unsigned short bf16_of(float x) {
    unsigned u = __float_as_uint(x);
    return (unsigned short)((u + 0x7fffu + ((u >> 16) & 1u)) >> 16);
}

__device__ __forceinline__ unsigned pack_bf16x2(float x, float y) {
    unsigned ux = __float_as_uint(x);
    unsigned uy = __float_as_uint(y);
    ux = (ux + 0x7fffu + ((ux >> 16) & 1u)) >> 16;          // RNE
    uy = (uy + 0x7fffu + ((uy >> 16) & 1u)) & 0xffff0000u;  // RNE, keep high
    return ux | uy;
}

__device__ __forceinline__ float2 unpack_bf16x2(unsigned v) {
    float2 r;
    r.x = __uint_as_float(v << 16);
    r.y = __uint_as_float(v & 0xffff0000u);
    return r;
}

__device__ __forceinline__ unsigned short pack_fp8x2(float x, float y) {
    int v = __builtin_amdgcn_cvt_pk_fp8_f32(x, y, 0, false);   // low word
    return (unsigned short)(unsigned)v;
}

__device__ __forceinline__ float2 unpack_fp8x2(unsigned short v) {
    vf2 r = __builtin_amdgcn_cvt_pk_f32_fp8((int)(unsigned)v, false);
    float2 o;
    o.x = r[0];
    o.y = r[1];
    return o;
}

// ---------------- dtype probe ----------------
__global__ void k_detect(const int* __restrict__ p, int npairs, int* __restrict__ flag) {
    __shared__ int any32;
    if (threadIdx.x == 0) any32 = 0;
    __syncthreads();
    for (int i = threadIdx.x; i < npairs; i += blockDim.x)
        if (p[2 * i + 1] != 0) any32 = 1;
    __syncthreads();
    if (threadIdx.x == 0) *flag = any32 ? 0 : 1;   // 1 => int64
}

// ---------------- preprocessing ----------------

__global__ void k_zero_i32(int* __restrict__ p, int n) {
    int i = blockIdx.x * blockDim.x + threadIdx.x;
    if (i < n) p[i] = 0;
}

__global__ void k_dinv(const int* __restrict__ cnt, float* __restrict__ dinv, int N) {
    int i = blockIdx.x * blockDim.x + threadIdx.x;
    if (i < N) dinv[i] = rsqrtf((float)(cnt[i] + 1));
}

__global__ void k_scan1(const int* __restrict__ cnt, int* __restrict__ rp,
                        int* __restrict__ bsum, int N) {
    __shared__ int s[256];
    int t = threadIdx.x;
    int i = blockIdx.x * 256 + t;
    int v = (i < N) ? (cnt[i] + 1) : 0;   // +1 self-loop slot
    s[t] = v;
    __syncthreads();
    for (int off = 1; off < 256; off <<= 1) {
        int add = (t >= off) ? s[t - off] : 0;
        __syncthreads();
        s[t] += add;
        __syncthreads();
    }
    if (i < N) rp[i] = s[t] - v;
    if (t == 255) bsum[blockIdx.x] = s[255];
}

__global__ void k_scan2(int* __restrict__ bsum, int nb) {
    __shared__ int s[512];
    int t = threadIdx.x;
    int v = (t < nb) ? bsum[t] : 0;
    s[t] = v;
    __syncthreads();
    for (int off = 1; off < 512; off <<= 1) {
        int add = (t >= off) ? s[t - off] : 0;
        __syncthreads();
        s[t] += add;
        __syncthreads();
    }
    if (t < nb) bsum[t] = s[t] - v;
}

__global__ void k_scan3(int* __restrict__ rp, const int* __restrict__ bsum,
                        int* __restrict__ col, int N, int Etot) {
    int i = blockIdx.x * blockDim.x + threadIdx.x;
    if (i < N) {
        int r = rp[i] + bsum[i >> 8];
        rp[i] = r;
        col[r] = i;          // self-loop first in each row (weightless)
    }
    if (i == 0) rp[N] = Etot;
}

// ---------------- binned two-phase placement ----------------

// bin histogram (dst/BSZ) -> bcnt[nbk]
__global__ __launch_bounds__(256) void k_bhist(const void* __restrict__ ei, int E,
                                               int* __restrict__ bcnt,
                                               const int* __restrict__ flag, int nbk) {
    __shared__ int h[1024];
    int is64 = *flag;
    for (int i = threadIdx.x; i < nbk; i += 256) h[i] = 0;
    __syncthreads();
    for (int e = blockIdx.x * 256 + threadIdx.x; e < E; e += gridDim.x * 256) {
        int d = idx_at(ei, (size_t)E + e, is64);
        atomicAdd(&h[d / BSZ], 1);
    }
    __syncthreads();
    for (int i = threadIdx.x; i < nbk; i += 256)
        if (h[i]) atomicAdd(&bcnt[i], h[i]);
}

// exclusive scan of bcnt -> bbase[nbk+1], gcur
__global__ void k_bscan(const int* __restrict__ bcnt, int* __restrict__ bbase,
                        int* __restrict__ gcur, int nbk, int E) {
    __shared__ int s[1024];
    int t = threadIdx.x;
    int v = (t < nbk) ? bcnt[t] : 0;
    s[t] = v;
    __syncthreads();
    for (int off = 1; off < 1024; off <<= 1) {
        int add = (t >= off) ? s[t - off] : 0;
        __syncthreads();
        s[t] += add;
        __syncthreads();
    }
    if (t < nbk) {
        bbase[t] = s[t] - v;
        gcur[t]  = s[t] - v;
    }
    if (t == 0) bbase[nbk] = E;
}

// phase A: bin edges into tmp (bin-contiguous, per-block runs)
__global__ __launch_bounds__(256) void k_binA(const void* __restrict__ ei, int E,
                                              int* __restrict__ gcur,
                                              int2* __restrict__ tmp,
                                              const int* __restrict__ flag, int nbk) {
    __shared__ int hA[1024], hB[1024], sbase[1024];
    int is64 = *flag;
    for (int i = threadIdx.x; i < nbk; i += 256) { hA[i] = 0; hB[i] = 0; }
    __syncthreads();
    const int e0 = (blockIdx.x * 256 + threadIdx.x) * 4;
    int s[4], d[4], b[4];
    const int n = (e0 < E) ? min(4, E - e0) : 0;
#pragma unroll
    for (int k = 0; k < 4; ++k)
        if (k < n) {
            s[k] = idx_at(ei, (size_t)(e0 + k), is64);
            d[k] = idx_at(ei, (size_t)E + (e0 + k), is64);
            b[k] = d[k] / BSZ;
            atomicAdd(&hA[b[k]], 1);
        }
    __syncthreads();
    for (int i = threadIdx.x; i < nbk; i += 256)
        sbase[i] = hA[i] ? atomicAdd(&gcur[i], hA[i]) : 0;
    __syncthreads();
#pragma unroll
    for (int k = 0; k < 4; ++k)
        if (k < n) {
            int off = atomicAdd(&hB[b[k]], 1);
            int2 p;
            p.x = s[k];
            p.y = d[k];
            tmp[sbase[b[k]] + off] = p;
        }
}

// per-bin count from tmp: LDS atomics + coalesced cnt write (replaces k_count)
__global__ __launch_bounds__(256) void k_bincnt(const int2* __restrict__ tmp,
                                                const int* __restrict__ bbase,
                                                int* __restrict__ cnt, int N) {
    __shared__ int lc[BSZ];
    const int b  = blockIdx.x;
    const int lo = b * BSZ;
    const int n  = min(BSZ, N - lo);
    for (int i = threadIdx.x; i < n; i += 256) lc[i] = 0;
    __syncthreads();
    const int start = bbase[b], end = bbase[b + 1];
    for (int i = start + threadIdx.x; i < end; i += 256)
        atomicAdd(&lc[tmp[i].y - lo], 1);
    __syncthreads();
    for (int i = threadIdx.x; i < n; i += 256) cnt[lo + i] = lc[i];
}

// phase B: one workgroup per bin; LDS cursor; scatter into local cw window
__global__ __launch_bounds__(256) void k_binB(const int2* __restrict__ tmp,
                                              const int* __restrict__ bbase,
                                              const int* __restrict__ rp,
                                              int* __restrict__ col, int N) {
    __shared__ int lcur[BSZ];
    const int b  = blockIdx.x;
    const int lo = b * BSZ;
    const int cnt = min(BSZ, N - lo);
    for (int i = threadIdx.x; i < cnt; i += 256) lcur[i] = 1;   // slot 0 = self-loop
    __syncthreads();
    const int start = bbase[b], end = bbase[b + 1];
    for (int i = start + threadIdx.x; i < end; i += 256) {
        int2 p = tmp[i];
        int off = atomicAdd(&lcur[p.y - lo], 1);
        col[rp[p.y] + off] = p.x;
    }
}

// ---------------- W transpose+cvt: Wt[c][k] = bf16(W[k][c]), W is [K][128] ----------------
__global__ void k_wt(const float* __restrict__ W, unsigned short* __restrict__ Wt, int K) {
    int i = blockIdx.x * blockDim.x + threadIdx.x;
    if (i < K * 128) {
        int k = i >> 7, c = i & 127;
        Wt[c * K + k] = bf16_of(W[i]);
    }
}

// ---------------- MFMA GEMM: y0 fp8 (= dinv*h) + alpha*h bf16 ----------------

template <int KTOT, bool AF32>
__global__ __launch_bounds__(256) void k_gemm_mfma(const void* __restrict__ Ap,
                                                   const unsigned short* __restrict__ Wt,
                                                   const float* __restrict__ dinv,
                                                   unsigned short* __restrict__ z0,
                                                   unsigned* __restrict__ ah, int N) {
    __shared__ __align__(16) char smem[64 * 132 * 4];
    unsigned short (*As)[40] = (unsigned short(*)[40])smem;            // 64 x 32 (+8 pad)
    unsigned short (*Bs)[40] = (unsigned short(*)[40])(smem + 5120);   // 128 x 32 (+8 pad), [col][k]
    float (*Cs)[132] = (float(*)[132])smem;

    const int t    = threadIdx.x;
    const int lane = t & 63;
    const int w    = t >> 6;
    const int wr   = w >> 1;
    const int wc   = w & 1;
    const int r0   = blockIdx.x * 64;

    f32x4 acc[2][4];
#pragma unroll
    for (int i = 0; i < 2; ++i)
#pragma unroll
        for (int j = 0; j < 4; ++j)
#pragma unroll
            for (int q = 0; q < 4; ++q) acc[i][j][q] = 0.f;

    const int arow = t >> 2;
    const int akc  = (t & 3) * 8;
    const int bcol = t >> 1;
    const int bkc  = (t & 1) * 16;

    for (int k0 = 0; k0 < KTOT; k0 += 32) {
        {
            int gr = r0 + arow;
            if (AF32) {
                uint4 s = make_uint4(0, 0, 0, 0);
                if (gr < N) {
                    const float* a = (const float*)Ap + (size_t)gr * KTOT + k0 + akc;
                    float4 v0 = *(const float4*)a;
                    float4 v1 = *(const float4*)(a + 4);
                    s.x = pack_bf16x2(v0.x, v0.y);
                    s.y = pack_bf16x2(v0.z, v0.w);
                    s.z = pack_bf16x2(v1.x, v1.y);
                    s.w = pack_bf16x2(v1.z, v1.w);
                }
                *(uint4*)&As[arow][akc] = s;
            } else {
                uint4 s = make_uint4(0, 0, 0, 0);
                if (gr < N) s = *(const uint4*)((const unsigned short*)Ap + (size_t)gr * KTOT + k0 + akc);
                *(uint4*)&As[arow][akc] = s;
            }
        }
        {
            const unsigned short* wsrc = Wt + (size_t)bcol * KTOT + k0 + bkc;
            *(uint4*)&Bs[bcol][bkc]     = *(const uint4*)wsrc;
            *(uint4*)&Bs[bcol][bkc + 8] = *(const uint4*)(wsrc + 8);
        }
        __syncthreads();
        {
            const int kblk = (lane >> 4) * 8;
            const int l15  = lane & 15;
            bf16x8 af[2], bfr[4];
#pragma unroll
            for (int i = 0; i < 2; ++i)
                af[i] = *(const bf16x8*)&As[wr * 32 + i * 16 + l15][kblk];
#pragma unroll
            for (int j = 0; j < 4; ++j)
                bfr[j] = *(const bf16x8*)&Bs[wc * 64 + j * 16 + l15][kblk];
#pragma unroll
            for (int i = 0; i < 2; ++i)
#pragma unroll
                for (int j = 0; j < 4; ++j)
                    acc[i][j] = __builtin_amdgcn_mfma_f32_16x16x32_bf16(af[i], bfr[j], acc[i][j], 0, 0, 0);
        }
        __syncthreads();
    }

    {
        const int l15 = lane & 15;
        const int rq  = (lane >> 4) * 4;
#pragma unroll
        for (int i = 0; i < 2; ++i)
#pragma unroll
            for (int j = 0; j < 4; ++j)
#pragma unroll
                for (int q = 0; q < 4; ++q)
                    Cs[wr * 32 + i * 16 + rq + q][wc * 64 + j * 16 + l15] = acc[i][j][q];
    }
    __syncthreads();
    {
        const int row = t >> 2;
        const int cb  = (t & 3) * 32;
        const int gr  = r0 + row;
        if (gr < N) {
            float dv = dinv[gr];
            float c[32];
#pragma unroll
            for (int m = 0; m < 8; ++m) {
                float4 v = *(const float4*)&Cs[row][cb + m * 4];
                c[m * 4 + 0] = v.x; c[m * 4 + 1] = v.y; c[m * 4 + 2] = v.z; c[m * 4 + 3] = v.w;
            }
            unsigned pk[8];
#pragma unroll
            for (int m = 0; m < 8; ++m) {
                unsigned lo = (unsigned)pack_fp8x2(dv * c[4 * m + 0], dv * c[4 * m + 1]);
                unsigned hi = (unsigned)pack_fp8x2(dv * c[4 * m + 2], dv * c[4 * m + 3]);
                pk[m] = lo | (hi << 16);
            }
            uint4* zd = (uint4*)&z0[((size_t)gr << 6) + (cb >> 1)];
            zd[0] = make_uint4(pk[0], pk[1], pk[2], pk[3]);
            zd[1] = make_uint4(pk[4], pk[5], pk[6], pk[7]);
            unsigned am[16];
#pragma unroll
            for (int m = 0; m < 16; ++m)
                am[m] = pack_bf16x2(A_ * c[2 * m], A_ * c[2 * m + 1]);
            uint4* ad = (uint4*)&ah[((size_t)gr << 6) + (cb >> 1)];
            ad[0] = make_uint4(am[0],  am[1],  am[2],  am[3]);
            ad[1] = make_uint4(am[4],  am[5],  am[6],  am[7]);
            ad[2] = make_uint4(am[8],  am[9],  am[10], am[11]);
            ad[3] = make_uint4(am[12], am[13], am[14], am[15]);
        }
    }
}

// ---------------- propagation hop (weightless gather of y rows) ----------------
// z_next = 0.9*dinv[d]*S + 0.1h, S = sum y[src] (incl self); y_next = dinv*z_next.
// OUTM: 0 = fp8 y, 1 = bf16 z, 3 = relu+bf16 z.

template <int B>
__device__ __forceinline__ void hop_batch(const unsigned short* __restrict__ yb,
                                          const int* __restrict__ col,
                                          int e, int lane,
                                          float& ax, float& ay,
                                          float& bx, float& by) {
    int c[B];
#pragma unroll
    for (int k = 0; k < B; ++k) c[k] = col[e + k];
    unsigned short v[B];
#pragma unroll
    for (int k = 0; k < B; ++k) v[k] = yb[((unsigned)c[k] << 6) + lane];
#pragma unroll
    for (int k = 0; k < B; ++k) {
        float2 z = unpack_fp8x2(v[k]);
        if (k & 1) { bx += z.x; by += z.y; }
        else       { ax += z.x; ay += z.y; }
    }
}

template <int OUTM>
__global__ __launch_bounds__(256) void k_hop(const unsigned short* __restrict__ yin,
                                             const unsigned* __restrict__ ah,
                                             const float* __restrict__ dinv,
                                             void* __restrict__ zout,
                                             const int* __restrict__ rp,
                                             const int* __restrict__ col, int N) {
    int wid  = (blockIdx.x * blockDim.x + threadIdx.x) >> 6;
    int lane = threadIdx.x & 63;
    if (wid >= N) return;

    int e   = __builtin_amdgcn_readfirstlane(rp[wid]);
    int end = __builtin_amdgcn_readfirstlane(rp[wid + 1]);
    float dv = dinv[wid];

    float2 hh = unpack_bf16x2(ah[((size_t)wid << 6) + lane]);

    float ax = 0.f, ay = 0.f, bx = 0.f, by = 0.f;

    for (; e + 16 <= end; e += 16)
        hop_batch<16>(yin, col, e, lane, ax, ay, bx, by);
    if (e + 8 <= end) { hop_batch<8>(yin, col, e, lane, ax, ay, bx, by); e += 8; }
    if (e + 4 <= end) { hop_batch<4>(yin, col, e, lane, ax, ay, bx, by); e += 4; }
    for (; e < end; ++e) {
        float2 z = unpack_fp8x2(yin[((unsigned)col[e] << 6) + lane]);
        ax += z.x; ay += z.y;
    }

    float q  = OMA * dv;
    float ox = q * (ax + bx) + hh.x;   // = z_next
    float oy = q * (ay + by) + hh.y;
    if (OUTM == 0) {
        ((unsigned short*)zout)[((size_t)wid << 6) + lane] = pack_fp8x2(dv * ox, dv * oy);
    } else if (OUTM == 1) {
        ((unsigned*)zout)[((size_t)wid << 6) + lane] = pack_bf16x2(ox, oy);
    } else {
        ((unsigned*)zout)[((size_t)wid << 6) + lane] =
            pack_bf16x2(fmaxf(ox, 0.f), fmaxf(oy, 0.f));
    }
}

// ---------------- decode: out[j] = dot(z[e0[j]], z[e1[j]]), z bf16 ----------------

__global__ __launch_bounds__(256) void k_decode(const unsigned* __restrict__ z,
                                                const void* __restrict__ pos,
                                                const void* __restrict__ neg,
                                                float* __restrict__ out, int P, int Q,
                                                const int* __restrict__ flag) {
    int is64 = *flag;
    int t   = blockIdx.x * blockDim.x + threadIdx.x;
    int j   = t >> 4;
    int sub = t & 15;
    if (j >= P + Q) return;
    int a, b;
    if (j < P) { a = idx_at(pos, (size_t)j, is64); b = idx_at(pos, (size_t)P + j, is64); }
    else       { int jj = j - P; a = idx_at(neg, (size_t)jj, is64); b = idx_at(neg, (size_t)Q + jj, is64); }
    const uint4* za = (const uint4*)&z[(size_t)a << 6];
    const uint4* zb = (const uint4*)&z[(size_t)b << 6];
    uint4 va = za[sub];
    uint4 vb = zb[sub];
    float s = 0.f;
    {
        float2 xa, xb;
        xa = unpack_bf16x2(va.x); xb = unpack_bf16x2(vb.x);
        s += xa.x * xb.x + xa.y * xb.y;
        xa = unpack_bf16x2(va.y); xb = unpack_bf16x2(vb.y);
        s += xa.x * xb.x + xa.y * xb.y;
        xa = unpack_bf16x2(va.z); xb = unpack_bf16x2(vb.z);
        s += xa.x * xb.x + xa.y * xb.y;
        xa = unpack_bf16x2(va.w); xb = unpack_bf16x2(vb.w);
        s += xa.x * xb.x + xa.y * xb.y;
    }
#pragma unroll
    for (int off = 8; off >= 1; off >>= 1) s += __shfl_xor(s, off, 16);
    if (sub == 0) out[j] = s;
}

// ---------------- launch ----------------

extern "C" void kernel_launch(void* const* d_in, const int* in_sizes, int n_in,
                              void* d_out, int out_size, void* d_ws, size_t ws_size,
                              hipStream_t stream) {
    const float* x   = (const float*)d_in[0];
    const void*  ei  = d_in[1];
    const void*  pos = d_in[2];
    const void*  neg = d_in[3];
    const float* W1  = (const float*)d_in[4];
    const float* W2  = (const float*)d_in[5];
    float*       out = (float*)d_out;

    const int N = in_sizes[0] / Fin;
    const int E = in_sizes[1] / 2;
    const int P = in_sizes[2] / 2;
    const int Q = in_sizes[3] / 2;
    const int Etot = E + N;
    const int nbk  = (N + BSZ - 1) / BSZ;   // 261 for N=100000 (cap 1024)

    char*  ws  = (char*)d_ws;
    size_t off = 0;
    auto carve = [&](size_t bytes) -> void* {
        void* p = ws + off;
        off = (off + bytes + 511) & ~(size_t)511;
        return p;
    };
    unsigned short* f0   = (unsigned short*)carve((size_t)N * 64 * 2);
    unsigned short* f1   = (unsigned short*)carve((size_t)N * 64 * 2);
    unsigned*       zB2  = (unsigned*)carve((size_t)N * 64 * 4);   // bf16 final (decode)
    unsigned*       zRB  = (unsigned*)carve((size_t)N * 64 * 4);   // relu bf16 (L2 GEMM A)
    unsigned*       ah   = (unsigned*)carve((size_t)N * 64 * 4);
    unsigned short* Wt1  = (unsigned short*)carve((size_t)128 * 256 * 2);
    unsigned short* Wt2  = (unsigned short*)carve((size_t)128 * 128 * 2);
    float*          dinv = (float*)carve((size_t)N * 4);
    int*     cnt    = (int*)carve((size_t)N * 4);
    int*     rp     = (int*)carve((size_t)(N + 1) * 4);
    int*     col    = (int*)carve((size_t)Etot * 4);
    int2*    tmp    = (int2*)carve((size_t)E * 8);
    int*     bcnt   = (int*)carve((size_t)nbk * 4);
    int*     bbase  = (int*)carve((size_t)(nbk + 1) * 4);
    int*     gcur   = (int*)carve((size_t)nbk * 4);
    int      nb     = (N + 255) / 256;
    int*     bsum   = (int*)carve((size_t)nb * 4);
    int*     flag   = (int*)carve(4);
    (void)ws_size;

    const int gN = (N + 255) / 256;

    k_detect<<<1, 256, 0, stream>>>((const int*)ei, 4096, flag);
    k_zero_i32<<<(nbk + 255) / 256, 256, 0, stream>>>(bcnt, nbk);
    // binned build: partition edges, derive counts from bins (no random atomics)
    k_bhist<<<512, 256, 0, stream>>>(ei, E, bcnt, flag, nbk);
    k_bscan<<<1, 1024, 0, stream>>>(bcnt, bbase, gcur, nbk, E);
    k_binA<<<(E + 1023) / 1024, 256, 0, stream>>>(ei, E, gcur, tmp, flag, nbk);
    k_bincnt<<<nbk, 256, 0, stream>>>(tmp, bbase, cnt, N);
    k_dinv<<<gN, 256, 0, stream>>>(cnt, dinv, N);
    k_scan1<<<nb, 256, 0, stream>>>(cnt, rp, bsum, N);
    k_scan2<<<1, 512, 0, stream>>>(bsum, nb);
    k_scan3<<<gN, 256, 0, stream>>>(rp, bsum, col, N, Etot);
    k_binB<<<nbk, 256, 0, stream>>>(tmp, bbase, rp, col, N);
    k_wt<<<(256 * 128 + 255) / 256, 256, 0, stream>>>(W1, Wt1, Fin);
    k_wt<<<(128 * 128 + 255) / 256, 256, 0, stream>>>(W2, Wt2, Hd);

    const int gGemm = (N + 63) / 64;
    const int gHop  = (N * 64 + 255) / 256;

    unsigned short* fb[2] = {f0, f1};

    // ---- layer 1: GEMM(y0 fp8 + ah) -> 9 fp8 hops -> final hop writes relu-bf16 z ----
    k_gemm_mfma<Fin, true><<<gGemm, 256, 0, stream>>>(x, Wt1, dinv, f0, ah, N);
    for (int k = 0; k < 9; ++k)
        k_hop<0><<<gHop, 256, 0, stream>>>(fb[k & 1], ah, dinv, fb[(k + 1) & 1], rp, col, N);
    k_hop<3><<<gHop, 256, 0, stream>>>(f1, ah, dinv, zRB, rp, col, N);

    // ---- layer 2: GEMM -> 9 fp8 hops -> final hop writes bf16 z ----
    k_gemm_mfma<Hd, false><<<gGemm, 256, 0, stream>>>(zRB, Wt2, dinv, f0, ah, N);
    for (int k = 0; k < 9; ++k)
        k_hop<0><<<gHop, 256, 0, stream>>>(fb[k & 1], ah, dinv, fb[(k + 1) & 1], rp, col, N);
    k_hop<1><<<gHop, 256, 0, stream>>>(f1, ah, dinv, zB2, rp, col, N);

    // ---- decode (bf16 z) ----
    const int gDec = ((P + Q) * 16 + 255) / 256;
    k_decode<<<gDec, 256, 0, stream>>>(zB2, pos, neg, out, P, Q, flag);
}